// Round 4
// baseline (547.721 us; speedup 1.0000x reference)
//
#include <hip/hip_runtime.h>
#include <hip/hip_bf16.h>
#include <stdint.h>

// STAR-DNN: per-sample scene-selected 3-layer MLP.
// R3: single persistent mega-kernel (occupancy-sized grid, manual device-scope
// grid barrier) -> 2 dispatches total. x gathered+bf16-converted ONCE into
// compacted xc; all 3 GEMM layers use the clean global_load_lds DMA path.

#define BATCH   16384
#define NSCENE  7
#define TM      128
#define NBLK    (BATCH / 256)            // 64 count/scatter jobs
#define PADMAX  (BATCH + NSCENE * TM)    // 17280 padded rows max

typedef __bf16 bf16x8 __attribute__((ext_vector_type(8)));
typedef float  f32x4  __attribute__((ext_vector_type(4)));

__device__ __forceinline__ ushort f2bf(float f) {
  union { float f; uint32_t u; } v; v.f = f;
  uint32_t r = (v.u + 0x7FFFu + ((v.u >> 16) & 1u)) >> 16;  // RNE
  return (ushort)r;
}
__device__ __forceinline__ uint32_t pk2(float a, float b) {
  union { __hip_bfloat162 h; uint32_t u; } cv;
  cv.h = __float22bfloat162_rn(make_float2(a, b));   // v_cvt_pk_bf16_f32
  return cv.u;
}
__device__ __forceinline__ void async16(const void* g, void* lds) {
  __builtin_amdgcn_global_load_lds(
      (const __attribute__((address_space(1))) uint32_t*)g,
      (__attribute__((address_space(3))) uint32_t*)lds, 16, 0, 0);
}

// device-scope grid barrier: all blocks co-resident (occupancy-sized grid).
__device__ __forceinline__ void gsync(int* bar, int G, int gen) {
  __syncthreads();
  __threadfence();                                   // release our stores
  if (threadIdx.x == 0) {
    __hip_atomic_fetch_add(bar, 1, __ATOMIC_ACQ_REL, __HIP_MEMORY_SCOPE_AGENT);
    while (__hip_atomic_load(bar, __ATOMIC_ACQUIRE, __HIP_MEMORY_SCOPE_AGENT) < G * gen)
      __builtin_amdgcn_s_sleep(2);
  }
  __syncthreads();
  __threadfence();                                   // acquire for our reads
}

#define NB_W0 (16 * 16 * 7)
#define NB_W1 (8 * 16 * 7)
#define NB_W2 (2 * 8 * 7)
#define NB_BIAS 23
#define NB_PREP (NB_W0 + NB_W1 + NB_W2 + NB_BIAS + NBLK)

// sT[s][n][k] = bf16(W[s][k][n] * gW[0][k][n]);  32x32 tile, 256 thr.
__device__ __forceinline__ void st_tile(const float* __restrict__ W,
                                        const float* __restrict__ gW,
                                        ushort* __restrict__ sT,
                                        float (*tl)[33],
                                        int K, int N, int s, int n0, int k0,
                                        int tid) {
  int tx = tid & 31, ty = tid >> 5;
  const float* Wp = W + (size_t)s * K * N;
#pragma unroll
  for (int i = 0; i < 4; i++) {
    int k = k0 + ty + i * 8;
    tl[ty + i * 8][tx] = Wp[(size_t)k * N + n0 + tx] * gW[(size_t)k * N + n0 + tx];
  }
  __syncthreads();
#pragma unroll
  for (int i = 0; i < 4; i++) {
    int n = n0 + ty + i * 8;
    sT[((size_t)s * N + n) * K + k0 + tx] = f2bf(tl[tx][ty + i * 8]);
  }
  __syncthreads();   // tl reused by next job
}

// ---- GEMM phase: C[tiles x NDIM] = A @ sT^T ------------------------------
// XOR-swizzled LDS (16B chunks): chunk c=row*8+q holds global kchunk
// q^(row&7); staging linear-in-lane -> global_load_lds; frag reads 2-way.
template<int KDIM, int NDIM, int TN, int NBJ, bool RELU, bool SCATTER_OUT>
__device__ __forceinline__ void gemm_phase(
    const ushort* __restrict__ ain, const ushort* __restrict__ bw,
    const float* __restrict__ bias, const int* __restrict__ meta,
    const int* __restrict__ idxp, ushort* __restrict__ hout,
    float* __restrict__ out, ushort* Abuf, ushort* Bbuf,
    int ntiles, int G, int bid, int tid) {
  constexpr int WN = TN / 2;
  constexpr int ACCN = WN / 16;
  int lane = tid & 63, wid = tid >> 6;
  int wm = wid >> 1, wn = wid & 1;

  for (int j = bid; j < ntiles * NBJ; j += G) {
    int t = j / NBJ, nb = j % NBJ;
    int sc = meta[32 + t];
    int mrow0 = meta[192 + t];

    f32x4 acc[4][ACCN];
#pragma unroll
    for (int mt = 0; mt < 4; mt++)
#pragma unroll
      for (int nt = 0; nt < ACCN; nt++) acc[mt][nt] = (f32x4){0.f, 0.f, 0.f, 0.f};

    const ushort* bwS = bw + ((size_t)sc * NDIM + (size_t)nb * TN) * KDIM;

    for (int kb = 0; kb < KDIM / 64; kb++) {
#pragma unroll
      for (int i = 0; i < 4; i++) {           // A tile (TM x 64)
        int c = tid + i * 256;
        int row = c >> 3, q = c & 7;
        int kg = q ^ (row & 7);
        async16(ain + (size_t)(mrow0 + row) * KDIM + kb * 64 + kg * 8,
                &Abuf[(size_t)(i * 256 + wid * 64) * 8]);
      }
#pragma unroll
      for (int i = 0; i < TN * 8 / 256; i++) { // B tile (TN x 64)
        int c = tid + i * 256;
        int row = c >> 3, q = c & 7;
        int kg = q ^ (row & 7);
        async16(bwS + (size_t)row * KDIM + kb * 64 + kg * 8,
                &Bbuf[(size_t)(i * 256 + wid * 64) * 8]);
      }
      __syncthreads();
#pragma unroll
      for (int kk = 0; kk < 64; kk += 32) {
        bf16x8 af[4], bfr[ACCN];
        int kc = (kk >> 3) + (lane >> 4);
#pragma unroll
        for (int mt = 0; mt < 4; mt++) {
          int row = wm * 64 + mt * 16 + (lane & 15);
          af[mt] = *(const bf16x8*)(&Abuf[(row * 8 + (kc ^ (row & 7))) * 8]);
        }
#pragma unroll
        for (int nt = 0; nt < ACCN; nt++) {
          int row = wn * WN + nt * 16 + (lane & 15);
          bfr[nt] = *(const bf16x8*)(&Bbuf[(row * 8 + (kc ^ (row & 7))) * 8]);
        }
#pragma unroll
        for (int mt = 0; mt < 4; mt++)
#pragma unroll
          for (int nt = 0; nt < ACCN; nt++)
            acc[mt][nt] = __builtin_amdgcn_mfma_f32_16x16x32_bf16(af[mt], bfr[nt], acc[mt][nt], 0, 0, 0);
      }
      __syncthreads();
    }

    // epilogue: C/D layout col=lane&15, row=(lane>>4)*4+reg [m89-verified]
    int gidx[4][4];
    if (SCATTER_OUT) {
#pragma unroll
      for (int mt = 0; mt < 4; mt++)
#pragma unroll
        for (int r = 0; r < 4; r++)
          gidx[mt][r] = idxp[mrow0 + wm * 64 + mt * 16 + (lane >> 4) * 4 + r];
    }
#pragma unroll
    for (int mt = 0; mt < 4; mt++) {
      int rl0 = wm * 64 + mt * 16 + (lane >> 4) * 4;
#pragma unroll
      for (int nt = 0; nt < ACCN; nt++) {
        int col = nb * TN + wn * WN + nt * 16 + (lane & 15);
        float bv = bias[sc * NDIM + col];
#pragma unroll
        for (int r = 0; r < 4; r++) {
          float v = acc[mt][nt][r] + bv;
          if (RELU) v = fmaxf(v, 0.f);
          if (SCATTER_OUT) {
            int g = gidx[mt][r];
            if (g >= 0) out[(size_t)g * NDIM + col] = v;
          } else {
            hout[(size_t)(mrow0 + rl0 + r) * NDIM + col] = f2bf(v);
          }
        }
      }
    }
  }
}

__global__ void init_k(int* bar) { if (threadIdx.x == 0) *bar = 0; }

__global__ __launch_bounds__(256, 2) void mega_k(
    const float* __restrict__ x, const int* __restrict__ scene,
    const float* __restrict__ W0, const float* __restrict__ gW0,
    const float* __restrict__ W1, const float* __restrict__ gW1,
    const float* __restrict__ W2, const float* __restrict__ gW2,
    const float* __restrict__ b0, const float* __restrict__ gb0,
    const float* __restrict__ b1, const float* __restrict__ gb1,
    const float* __restrict__ b2, const float* __restrict__ gb2,
    ushort* __restrict__ sT0, ushort* __restrict__ sT1, ushort* __restrict__ sT2,
    float* __restrict__ bias0, float* __restrict__ bias1, float* __restrict__ bias2,
    int* __restrict__ bcnt, int* __restrict__ bbase, int* __restrict__ meta,
    int* __restrict__ idxp, int* __restrict__ destg, ushort* __restrict__ xc,
    ushort* __restrict__ hc1, ushort* __restrict__ hc2,
    float* __restrict__ out, int* bar) {
  __shared__ __align__(16) ushort Abuf[TM * 64];
  __shared__ __align__(16) ushort Bbuf[TM * 64];
  __shared__ float tl[32][33];
  __shared__ int shl[NSCENE];
  __shared__ int sdest[256];

  int G = gridDim.x, bid = blockIdx.x, tid = threadIdx.x;

  // ---- P0: weight scale+transpose, bias fuse, scene histogram ----
  for (int j = bid; j < NB_PREP; j += G) {
    if (j < NB_W0) {
      st_tile(W0, gW0, sT0, tl, 512, 512, j / 256, (j % 16) * 32, ((j / 16) % 16) * 32, tid);
    } else if (j < NB_W0 + NB_W1) {
      int l = j - NB_W0;
      st_tile(W1, gW1, sT1, tl, 512, 256, l / 128, (l % 8) * 32, ((l / 8) % 16) * 32, tid);
    } else if (j < NB_W0 + NB_W1 + NB_W2) {
      int l = j - NB_W0 - NB_W1;
      st_tile(W2, gW2, sT2, tl, 256, 64, l / 16, (l % 2) * 32, ((l / 2) % 8) * 32, tid);
    } else if (j < NB_W0 + NB_W1 + NB_W2 + NB_BIAS) {
      int t = (j - NB_W0 - NB_W1 - NB_W2) * 256 + tid;
      if (t < 7 * 512) bias0[t] = b0[t] + gb0[t & 511];
      else if (t < 7 * 512 + 7 * 256) { int i = t - 7 * 512; bias1[i] = b1[i] + gb1[i & 255]; }
      else if (t < 7 * 512 + 7 * 256 + 7 * 64) { int i = t - 7 * 512 - 7 * 256; bias2[i] = b2[i] + gb2[i & 63]; }
    } else {
      int blk = j - NB_W0 - NB_W1 - NB_W2 - NB_BIAS;
      if (tid < NSCENE) shl[tid] = 0;
      __syncthreads();
      atomicAdd(&shl[scene[blk * 256 + tid] - 1], 1);   // LDS atomic
      __syncthreads();
      if (tid < NSCENE) bcnt[blk * NSCENE + tid] = shl[tid];
      __syncthreads();
    }
  }
  gsync(bar, G, 1);

  // ---- P1: plan (block 0) ----
  if (bid == 0) {
    __shared__ int tot[NSCENE], pstart[NSCENE], pend[NSCENE];
    if (tid < NSCENE) {
      int c = 0;
      for (int b = 0; b < NBLK; b++) c += bcnt[b * NSCENE + tid];
      tot[tid] = c;
    }
    __syncthreads();
    if (tid == 0) {
      int po = 0, t = 0;
      for (int s = 0; s < NSCENE; s++) {
        meta[16 + s] = po;
        int tiles = (tot[s] + TM - 1) / TM;
        pstart[s] = po + tot[s];
        pend[s] = po + tiles * TM;
        for (int jj = 0; jj < tiles; jj++) { meta[32 + t] = s; meta[192 + t] = po + jj * TM; t++; }
        po += tiles * TM;
      }
      meta[24] = t;
    }
    __syncthreads();
    if (tid < NSCENE) {
      int run = meta[16 + tid];
      for (int b = 0; b < NBLK; b++) { bbase[b * NSCENE + tid] = run; run += bcnt[b * NSCENE + tid]; }
    }
    for (int s = 0; s < NSCENE; s++)
      for (int i = pstart[s] + tid; i < pend[s]; i += 256) idxp[i] = -1;
  }
  gsync(bar, G, 2);

  // ---- P2a: scatter ranks ----
  for (int j = bid; j < NBLK; j += G) {
    if (tid < NSCENE) shl[tid] = 0;
    __syncthreads();
    int i = j * 256 + tid;
    int s = scene[i] - 1;
    int pos = atomicAdd(&shl[s], 1);
    int dest = bbase[j * NSCENE + s] + pos;
    idxp[dest] = i;
    destg[i] = dest;
    __syncthreads();
  }
  gsync(bar, G, 3);

  // ---- P2b: build compacted bf16 xc (x converted once) ----
  for (int j = bid; j < BATCH / 8; j += G) {
    int base = j * 8;
    for (int k = tid; k < 512; k += 256) {   // 8 rows x 64 chunks(8 elem)
      int r = base + (k >> 6), c = k & 63;
      int d = destg[r];
      const float4* p = (const float4*)(x + (size_t)r * 512 + c * 8);
      float4 f0 = p[0], f1 = p[1];
      uint4 v;
      v.x = pk2(f0.x, f0.y); v.y = pk2(f0.z, f0.w);
      v.z = pk2(f1.x, f1.y); v.w = pk2(f1.z, f1.w);
      *(uint4*)(xc + (size_t)d * 512 + c * 8) = v;
    }
  }
  gsync(bar, G, 4);

  int ntiles = meta[24];

  // ---- P3..P5: the three GEMM layers ----
  gemm_phase<512, 512, 128, 4, true,  false>(xc,  sT0, bias0, meta, idxp, hc1, nullptr,
                                             Abuf, Bbuf, ntiles, G, bid, tid);
  gsync(bar, G, 5);
  gemm_phase<512, 256, 128, 2, true,  false>(hc1, sT1, bias1, meta, idxp, hc2, nullptr,
                                             Abuf, Bbuf, ntiles, G, bid, tid);
  gsync(bar, G, 6);
  gemm_phase<256, 64,  64,  1, false, true >(hc2, sT2, bias2, meta, idxp, nullptr, out,
                                             Abuf, Bbuf, ntiles, G, bid, tid);
}

extern "C" void kernel_launch(void* const* d_in, const int* in_sizes, int n_in,
                              void* d_out, int out_size, void* d_ws, size_t ws_size,
                              hipStream_t stream) {
  const float* x   = (const float*)d_in[0];
  const int* scene = (const int*)d_in[1];
  const float* W0  = (const float*)d_in[2];
  const float* b0  = (const float*)d_in[3];
  const float* gW0 = (const float*)d_in[4];
  const float* gb0 = (const float*)d_in[5];
  const float* W1  = (const float*)d_in[6];
  const float* b1  = (const float*)d_in[7];
  const float* gW1 = (const float*)d_in[8];
  const float* gb1 = (const float*)d_in[9];
  const float* W2  = (const float*)d_in[10];
  const float* b2  = (const float*)d_in[11];
  const float* gW2 = (const float*)d_in[12];
  const float* gb2 = (const float*)d_in[13];
  float* out = (float*)d_out;

  char* ws = (char*)d_ws;
  size_t off = 0;
  auto alloc = [&](size_t bytes) -> void* {
    void* p = ws + off;
    off = (off + bytes + 255) & ~(size_t)255;
    return p;
  };
  ushort* sT0   = (ushort*)alloc((size_t)7 * 512 * 512 * 2);
  ushort* sT1   = (ushort*)alloc((size_t)7 * 256 * 512 * 2);
  ushort* sT2   = (ushort*)alloc((size_t)7 * 64 * 256 * 2);
  float*  bias0 = (float*)alloc(7 * 512 * 4);
  float*  bias1 = (float*)alloc(7 * 256 * 4);
  float*  bias2 = (float*)alloc(7 * 64 * 4);
  int*    meta  = (int*)alloc(1024 * 4);
  int*    bcnt  = (int*)alloc(NBLK * NSCENE * 4);
  int*    bbase = (int*)alloc(NBLK * NSCENE * 4);
  int*    idxp  = (int*)alloc(PADMAX * 4);
  int*    destg = (int*)alloc(BATCH * 4);
  ushort* xc    = (ushort*)alloc((size_t)PADMAX * 512 * 2);
  ushort* hc1   = (ushort*)alloc((size_t)PADMAX * 512 * 2);
  ushort* hc2   = (ushort*)alloc((size_t)PADMAX * 256 * 2);
  int*    bar   = (int*)alloc(256);
  (void)ws_size; (void)n_in; (void)in_sizes; (void)out_size;

  // co-residency: occupancy-derived grid (deterministic each call)
  int occ = 0;
  (void)hipOccupancyMaxActiveBlocksPerMultiprocessor(&occ, mega_k, 256, 0);
  if (occ < 1) occ = 1;
  if (occ > 4) occ = 4;
  int G = occ * 256;

  init_k<<<1, 64, 0, stream>>>(bar);
  hipLaunchKernelGGL(mega_k, dim3(G), dim3(256), 0, stream,
                     x, scene, W0, gW0, W1, gW1, W2, gW2,
                     b0, gb0, b1, gb1, b2, gb2,
                     sT0, sT1, sT2, bias0, bias1, bias2,
                     bcnt, bbase, meta, idxp, destg, xc, hc1, hc2, out, bar);
}

// Round 5
// 170.107 us; speedup vs baseline: 3.2199x; 3.2199x over previous
//
#include <hip/hip_runtime.h>
#include <hip/hip_bf16.h>
#include <stdint.h>

// STAR-DNN: per-sample scene-selected 3-layer MLP.
// R1: LDS-histogram count/scatter (no global atomics).
// R2: global_load_lds DMA staging, fused prep.
// R4 (failed): persistent kernel + grid barriers = 140us/barrier on 8 XCDs.
// R5: back to multi-kernel; x compacted+bf16-converted ONCE (xc), so all
//     three GEMM layers use the pure global_load_lds DMA path.

#define BATCH   16384
#define NSCENE  7
#define TM      128
#define NBLK    (BATCH / 256)            // 64 count/scatter blocks
#define MT_MAX  (BATCH / TM + NSCENE)    // 135 worst-case tiles
#define PADMAX  (BATCH + NSCENE * TM)    // 17280 padded rows max

typedef __bf16 bf16x8 __attribute__((ext_vector_type(8)));
typedef float  f32x4  __attribute__((ext_vector_type(4)));

__device__ __forceinline__ ushort f2bf(float f) {
  union { float f; uint32_t u; } v; v.f = f;
  uint32_t r = (v.u + 0x7FFFu + ((v.u >> 16) & 1u)) >> 16;  // RNE
  return (ushort)r;
}
__device__ __forceinline__ uint32_t pk2(float a, float b) {
  union { __hip_bfloat162 h; uint32_t u; } cv;
  cv.h = __float22bfloat162_rn(make_float2(a, b));   // v_cvt_pk_bf16_f32
  return cv.u;
}
__device__ __forceinline__ void async16(const void* g, void* lds) {
  __builtin_amdgcn_global_load_lds(
      (const __attribute__((address_space(1))) uint32_t*)g,
      (__attribute__((address_space(3))) uint32_t*)lds, 16, 0, 0);
}

// ---- fused prep: W scale+transpose (x3), bias fuse, scene histogram ------
__device__ __forceinline__ void st_tile(const float* __restrict__ W,
                                        const float* __restrict__ gW,
                                        ushort* __restrict__ sT,
                                        int K, int N, int s, int n0, int k0,
                                        int tid) {
  __shared__ float tl[32][33];
  int tx = tid & 31, ty = tid >> 5;
  const float* Wp = W + (size_t)s * K * N;
#pragma unroll
  for (int i = 0; i < 4; i++) {
    int k = k0 + ty + i * 8;
    tl[ty + i * 8][tx] = Wp[(size_t)k * N + n0 + tx] * gW[(size_t)k * N + n0 + tx];
  }
  __syncthreads();
#pragma unroll
  for (int i = 0; i < 4; i++) {
    int n = n0 + ty + i * 8;
    sT[((size_t)s * N + n) * K + k0 + tx] = f2bf(tl[tx][ty + i * 8]);
  }
}

#define NB_W0 (16 * 16 * 7)
#define NB_W1 (8 * 16 * 7)
#define NB_W2 (2 * 8 * 7)
#define NB_BIAS 23
#define NB_CNT NBLK

__global__ __launch_bounds__(256) void prep_k(
    const float* __restrict__ W0, const float* __restrict__ gW0,
    const float* __restrict__ W1, const float* __restrict__ gW1,
    const float* __restrict__ W2, const float* __restrict__ gW2,
    const float* __restrict__ b0, const float* __restrict__ gb0,
    const float* __restrict__ b1, const float* __restrict__ gb1,
    const float* __restrict__ b2, const float* __restrict__ gb2,
    const int* __restrict__ scene,
    ushort* __restrict__ sT0, ushort* __restrict__ sT1, ushort* __restrict__ sT2,
    float* __restrict__ bias0, float* __restrict__ bias1, float* __restrict__ bias2,
    int* __restrict__ bcnt) {
  int bid = blockIdx.x, tid = threadIdx.x;
  if (bid < NB_W0) {
    int l = bid;
    st_tile(W0, gW0, sT0, 512, 512, l / 256, (l % 16) * 32, ((l / 16) % 16) * 32, tid);
  } else if (bid < NB_W0 + NB_W1) {
    int l = bid - NB_W0;
    st_tile(W1, gW1, sT1, 512, 256, l / 128, (l % 8) * 32, ((l / 8) % 16) * 32, tid);
  } else if (bid < NB_W0 + NB_W1 + NB_W2) {
    int l = bid - NB_W0 - NB_W1;
    st_tile(W2, gW2, sT2, 256, 64, l / 16, (l % 2) * 32, ((l / 2) % 8) * 32, tid);
  } else if (bid < NB_W0 + NB_W1 + NB_W2 + NB_BIAS) {
    int t = (bid - NB_W0 - NB_W1 - NB_W2) * 256 + tid;
    if (t < 7 * 512) bias0[t] = b0[t] + gb0[t & 511];
    else if (t < 7 * 512 + 7 * 256) { int i = t - 7 * 512; bias1[i] = b1[i] + gb1[i & 255]; }
    else if (t < 7 * 512 + 7 * 256 + 7 * 64) { int i = t - 7 * 512 - 7 * 256; bias2[i] = b2[i] + gb2[i & 63]; }
  } else {
    __shared__ int l[NSCENE];
    if (tid < NSCENE) l[tid] = 0;
    __syncthreads();
    int blk = bid - NB_W0 - NB_W1 - NB_W2 - NB_BIAS;
    atomicAdd(&l[scene[blk * 256 + tid] - 1], 1);   // LDS atomic
    __syncthreads();
    if (tid < NSCENE) bcnt[blk * NSCENE + tid] = l[tid];
  }
}

// meta: [16..23]=padoff [24]=ntiles [32..191]=tile_scene [192..351]=tile_row
__global__ void plan_k(const int* __restrict__ bcnt, int* __restrict__ meta,
                       int* __restrict__ bbase, int* __restrict__ idxp) {
  __shared__ int tot[NSCENE], pstart[NSCENE], pend[NSCENE];
  int tid = threadIdx.x;
  if (tid < NSCENE) {
    int c = 0;
    for (int b = 0; b < NBLK; b++) c += bcnt[b * NSCENE + tid];
    tot[tid] = c;
  }
  __syncthreads();
  if (tid == 0) {
    int po = 0, t = 0;
    for (int s = 0; s < NSCENE; s++) {
      meta[16 + s] = po;
      int tiles = (tot[s] + TM - 1) / TM;
      pstart[s] = po + tot[s];
      pend[s] = po + tiles * TM;
      for (int j = 0; j < tiles; j++) { meta[32 + t] = s; meta[192 + t] = po + j * TM; t++; }
      po += tiles * TM;
    }
    meta[24] = t;
  }
  __syncthreads();
  if (tid < NSCENE) {
    int run = meta[16 + tid];
    for (int b = 0; b < NBLK; b++) { bbase[b * NSCENE + tid] = run; run += bcnt[b * NSCENE + tid]; }
  }
  for (int s = 0; s < NSCENE; s++)
    for (int i = pstart[s] + tid; i < pend[s]; i += 256) idxp[i] = -1;
}

__global__ void scatter_k(const int* __restrict__ scene,
                          const int* __restrict__ bbase, int* __restrict__ idxp,
                          int* __restrict__ destg) {
  __shared__ int l[NSCENE];
  if (threadIdx.x < NSCENE) l[threadIdx.x] = 0;
  __syncthreads();
  int i = blockIdx.x * 256 + threadIdx.x;
  int s = scene[i] - 1;
  int pos = atomicAdd(&l[s], 1);    // LDS atomic: local rank
  int dest = bbase[blockIdx.x * NSCENE + s] + pos;
  idxp[dest] = i;
  destg[i] = dest;
}

// ---- xc build: compact + fp32->bf16 convert x ONCE -----------------------
// 2048 blocks x 256 thr; 32 threads/row, 16 elems (64B) per thread.
__global__ __launch_bounds__(256) void xc_k(const float* __restrict__ x,
                                            const int* __restrict__ destg,
                                            ushort* __restrict__ xc) {
  int r = blockIdx.x * 8 + (threadIdx.x >> 5);
  int c = (threadIdx.x & 31) * 16;
  int d = destg[r];
  const float4* p = (const float4*)(x + (size_t)r * 512 + c);
  float4 f0 = p[0], f1 = p[1], f2 = p[2], f3 = p[3];
  uint4 v0, v1;
  v0.x = pk2(f0.x, f0.y); v0.y = pk2(f0.z, f0.w);
  v0.z = pk2(f1.x, f1.y); v0.w = pk2(f1.z, f1.w);
  v1.x = pk2(f2.x, f2.y); v1.y = pk2(f2.z, f2.w);
  v1.z = pk2(f3.x, f3.y); v1.w = pk2(f3.z, f3.w);
  uint4* q = (uint4*)(xc + (size_t)d * 512 + c);
  q[0] = v0; q[1] = v1;
}

// ---- GEMM: C[tile rows x NDIM] = A @ sT^T, per-tile scene weights --------
// XOR-swizzled LDS (16B chunks): chunk c=row*8+q holds global kchunk
// q^(row&7); staging linear-in-lane -> global_load_lds; frag reads 2-way.
template<int KDIM, int NDIM, int TN, bool RELU, bool SCATTER_OUT>
__global__ __launch_bounds__(256) void gemm_k(
    const ushort* __restrict__ ain, const ushort* __restrict__ bw,
    const float* __restrict__ bias, const int* __restrict__ meta,
    const int* __restrict__ idxp, ushort* __restrict__ hout,
    float* __restrict__ out) {
  int t = blockIdx.x;
  if (t >= meta[24]) return;
  int sc = meta[32 + t];
  int mrow0 = meta[192 + t];
  int nb = blockIdx.y;

  constexpr int WN = TN / 2;
  constexpr int ACCN = WN / 16;

  __shared__ __align__(16) ushort Abuf[TM * 64];
  __shared__ __align__(16) ushort Bbuf[TN * 64];

  int tid = threadIdx.x;
  int lane = tid & 63, wid = tid >> 6;
  int wm = wid >> 1, wn = wid & 1;

  f32x4 acc[4][ACCN];
#pragma unroll
  for (int mt = 0; mt < 4; mt++)
#pragma unroll
    for (int nt = 0; nt < ACCN; nt++) acc[mt][nt] = (f32x4){0.f, 0.f, 0.f, 0.f};

  const ushort* bwS = bw + ((size_t)sc * NDIM + (size_t)nb * TN) * KDIM;

  for (int kb = 0; kb < KDIM / 64; kb++) {
#pragma unroll
    for (int i = 0; i < 4; i++) {             // A tile (TM x 64)
      int c = tid + i * 256;
      int row = c >> 3, q = c & 7;
      int kg = q ^ (row & 7);
      async16(ain + (size_t)(mrow0 + row) * KDIM + kb * 64 + kg * 8,
              &Abuf[(size_t)(i * 256 + wid * 64) * 8]);
    }
#pragma unroll
    for (int i = 0; i < TN * 8 / 256; i++) {  // B tile (TN x 64)
      int c = tid + i * 256;
      int row = c >> 3, q = c & 7;
      int kg = q ^ (row & 7);
      async16(bwS + (size_t)row * KDIM + kb * 64 + kg * 8,
              &Bbuf[(size_t)(i * 256 + wid * 64) * 8]);
    }
    __syncthreads();
#pragma unroll
    for (int kk = 0; kk < 64; kk += 32) {
      bf16x8 af[4], bfr[ACCN];
      int kc = (kk >> 3) + (lane >> 4);
#pragma unroll
      for (int mt = 0; mt < 4; mt++) {
        int row = wm * 64 + mt * 16 + (lane & 15);
        af[mt] = *(const bf16x8*)(&Abuf[(row * 8 + (kc ^ (row & 7))) * 8]);
      }
#pragma unroll
      for (int nt = 0; nt < ACCN; nt++) {
        int row = wn * WN + nt * 16 + (lane & 15);
        bfr[nt] = *(const bf16x8*)(&Bbuf[(row * 8 + (kc ^ (row & 7))) * 8]);
      }
#pragma unroll
      for (int mt = 0; mt < 4; mt++)
#pragma unroll
        for (int nt = 0; nt < ACCN; nt++)
          acc[mt][nt] = __builtin_amdgcn_mfma_f32_16x16x32_bf16(af[mt], bfr[nt], acc[mt][nt], 0, 0, 0);
    }
    __syncthreads();
  }

  // epilogue: C/D layout col=lane&15, row=(lane>>4)*4+reg [m89-verified]
  int gidx[4][4];
  if (SCATTER_OUT) {
#pragma unroll
    for (int mt = 0; mt < 4; mt++)
#pragma unroll
      for (int r = 0; r < 4; r++)
        gidx[mt][r] = idxp[mrow0 + wm * 64 + mt * 16 + (lane >> 4) * 4 + r];
  }
#pragma unroll
  for (int mt = 0; mt < 4; mt++) {
    int rl0 = wm * 64 + mt * 16 + (lane >> 4) * 4;
#pragma unroll
    for (int nt = 0; nt < ACCN; nt++) {
      int col = nb * TN + wn * WN + nt * 16 + (lane & 15);
      float bv = bias[sc * NDIM + col];
#pragma unroll
      for (int r = 0; r < 4; r++) {
        float v = acc[mt][nt][r] + bv;
        if (RELU) v = fmaxf(v, 0.f);
        if (SCATTER_OUT) {
          int g = gidx[mt][r];
          if (g >= 0) out[(size_t)g * NDIM + col] = v;
        } else {
          hout[(size_t)(mrow0 + rl0 + r) * NDIM + col] = f2bf(v);
        }
      }
    }
  }
}

extern "C" void kernel_launch(void* const* d_in, const int* in_sizes, int n_in,
                              void* d_out, int out_size, void* d_ws, size_t ws_size,
                              hipStream_t stream) {
  const float* x   = (const float*)d_in[0];
  const int* scene = (const int*)d_in[1];
  const float* W0  = (const float*)d_in[2];
  const float* b0  = (const float*)d_in[3];
  const float* gW0 = (const float*)d_in[4];
  const float* gb0 = (const float*)d_in[5];
  const float* W1  = (const float*)d_in[6];
  const float* b1  = (const float*)d_in[7];
  const float* gW1 = (const float*)d_in[8];
  const float* gb1 = (const float*)d_in[9];
  const float* W2  = (const float*)d_in[10];
  const float* b2  = (const float*)d_in[11];
  const float* gW2 = (const float*)d_in[12];
  const float* gb2 = (const float*)d_in[13];
  float* out = (float*)d_out;

  char* ws = (char*)d_ws;
  size_t off = 0;
  auto alloc = [&](size_t bytes) -> void* {
    void* p = ws + off;
    off = (off + bytes + 255) & ~(size_t)255;
    return p;
  };
  ushort* sT0   = (ushort*)alloc((size_t)7 * 512 * 512 * 2);
  ushort* sT1   = (ushort*)alloc((size_t)7 * 256 * 512 * 2);
  ushort* sT2   = (ushort*)alloc((size_t)7 * 64 * 256 * 2);
  float*  bias0 = (float*)alloc(7 * 512 * 4);
  float*  bias1 = (float*)alloc(7 * 256 * 4);
  float*  bias2 = (float*)alloc(7 * 64 * 4);
  int*    meta  = (int*)alloc(1024 * 4);
  int*    bcnt  = (int*)alloc(NBLK * NSCENE * 4);
  int*    bbase = (int*)alloc(NBLK * NSCENE * 4);
  int*    idxp  = (int*)alloc(PADMAX * 4);
  int*    destg = (int*)alloc(BATCH * 4);
  ushort* xc    = (ushort*)alloc((size_t)PADMAX * 512 * 2);
  ushort* hc1   = (ushort*)alloc((size_t)PADMAX * 512 * 2);
  ushort* hc2   = (ushort*)alloc((size_t)PADMAX * 256 * 2);
  (void)ws_size; (void)n_in; (void)in_sizes; (void)out_size;

  prep_k<<<NB_W0 + NB_W1 + NB_W2 + NB_BIAS + NB_CNT, 256, 0, stream>>>(
      W0, gW0, W1, gW1, W2, gW2, b0, gb0, b1, gb1, b2, gb2, scene,
      sT0, sT1, sT2, bias0, bias1, bias2, bcnt);
  plan_k<<<1, 256, 0, stream>>>(bcnt, meta, bbase, idxp);
  scatter_k<<<NBLK, 256, 0, stream>>>(scene, bbase, idxp, destg);
  xc_k<<<BATCH / 8, 256, 0, stream>>>(x, destg, xc);

  gemm_k<512, 512, 128, true,  false><<<dim3(MT_MAX, 4), 256, 0, stream>>>(
      xc, sT0, bias0, meta, idxp, hc1, nullptr);
  gemm_k<512, 256, 128, true,  false><<<dim3(MT_MAX, 2), 256, 0, stream>>>(
      hc1, sT1, bias1, meta, idxp, hc2, nullptr);
  gemm_k<256, 64,  64,  false, true ><<<dim3(MT_MAX, 1), 256, 0, stream>>>(
      hc2, sT2, bias2, meta, idxp, nullptr, out);
}